// Round 13
// baseline (146.980 us; speedup 1.0000x reference)
//
#include <hip/hip_runtime.h>
#include <hip/hip_bf16.h>
#include <stdint.h>

typedef __bf16 bf16_t;
typedef __attribute__((ext_vector_type(8))) __bf16 bf16x8;
typedef __attribute__((ext_vector_type(4))) __bf16 bf16x4;
typedef __attribute__((ext_vector_type(4))) float f32x4;

#define NHEADS 32
#define HDIM 128
#define NKV 8
#define GQ 4
#define BATCH 8
#define SEQ 1024
#define TOTAL (BATCH * SEQ)
#define QD (NHEADS * HDIM)   // 4096
#define KVD (NKV * HDIM)     // 1024
#define ATT_SCALE 0.08838834764831845f
#define QSCL (0.08838834764831845f * 1.4426950408889634f)

#define QBLK 64
#define KBLK 64
#define NQT (SEQ / QBLK)     // 16

__device__ __forceinline__ void gload16(const bf16_t* g, bf16_t* l) {
    __builtin_amdgcn_global_load_lds(
        (const __attribute__((address_space(1))) void*)g,
        (__attribute__((address_space(3))) void*)l,
        16, 0, 0);
}

// proven in m214v22 / v8: pack two f32 -> u32 of 2 bf16 (lo = src0, hi = src1)
__device__ __forceinline__ uint32_t cvt_pk_bf16(float lo, float hi) {
    uint32_t r;
    asm("v_cvt_pk_bf16_f32 %0, %1, %2" : "=v"(r) : "v"(lo), "v"(hi));
    return r;
}

// ===========================================================================
// Pre-pass: K fp32 -> bf16 (same layout); V fp32 -> bf16 TRANSPOSED with
// k-column PERMUTATION within each 64-token block:
//   k = (k5 k4 k3 k2 k1 k0) -> pos = k5<<5 | k3<<4 | k2<<3 | k4<<2 | k1 k0
// Makes the PV B-fragment (chunk ks*4+l4) match the k's a lane holds
// in-register after the swapped QK^T -> P->A pack is fully in-lane.
// ===========================================================================
__global__ __launch_bounds__(256)
void attn_prepass_kernel(const float* __restrict__ kg, const float* __restrict__ vg,
                         bf16_t* __restrict__ kws, bf16_t* __restrict__ vtws)
{
    const int bid = blockIdx.x;
    const int tid = threadIdx.x;
    if (bid < 512) {
        __shared__ bf16_t Lt[128 * 130];
        const int b  = bid >> 6;
        const int hk = (bid >> 3) & 7;
        const int tt = bid & 7;
        const float* vp = vg + ((long)(b * SEQ + tt * 128)) * KVD + hk * HDIM;
        #pragma unroll
        for (int it = 0; it < 16; ++it) {
            int idx = it * 256 + tid;
            int t  = idx >> 5;
            int c4 = (idx & 31) * 4;
            float4 f = *(const float4*)(vp + (long)t * KVD + c4);
            Lt[(c4 + 0) * 130 + t] = (bf16_t)f.x;
            Lt[(c4 + 1) * 130 + t] = (bf16_t)f.y;
            Lt[(c4 + 2) * 130 + t] = (bf16_t)f.z;
            Lt[(c4 + 3) * 130 + t] = (bf16_t)f.w;
        }
        __syncthreads();
        bf16_t* op = vtws + ((long)((b * NKV + hk) * HDIM)) * SEQ + tt * 128;
        #pragma unroll
        for (int jt = 0; jt < 8; ++jt) {
            int jdx = jt * 256 + tid;
            int d  = jdx >> 4;          // 0..127
            int c8 = (jdx & 15) * 8;    // 0..120 (8-aligned)
            const bf16_t* lp = &Lt[d * 130 + c8];
            uint32_t u0 = *(const uint32_t*)(lp + 0);
            uint32_t u1 = *(const uint32_t*)(lp + 2);
            uint32_t u2 = *(const uint32_t*)(lp + 4);
            uint32_t u3 = *(const uint32_t*)(lp + 6);
            // chunk base kl0 (bits k5,k4,k3) -> pos base p0 = k5<<5|k3<<4|k4<<2
            int kl0 = c8 & 63;
            int p0  = (kl0 & 32) | ((kl0 & 8) << 1) | ((kl0 & 16) >> 2);
            bf16_t* dst = op + (long)d * SEQ + (c8 & ~63);
            uint2 lo; lo.x = u0; lo.y = u1;     // k2=0: j=0..3
            uint2 hi; hi.x = u2; hi.y = u3;     // k2=1: j=0..3
            *(uint2*)(dst + p0)     = lo;
            *(uint2*)(dst + p0 + 8) = hi;
        }
    } else {
        const long total4 = (long)TOTAL * KVD / 4;
        const float4* k4 = (const float4*)kg;
        for (long i = (long)(bid - 512) * 256 + tid; i < total4; i += 1024L * 256) {
            float4 f = k4[i];
            bf16x4 o4;
            o4[0] = (bf16_t)f.x; o4[1] = (bf16_t)f.y;
            o4[2] = (bf16_t)f.z; o4[3] = (bf16_t)f.w;
            *(bf16x4*)(kws + i * 4) = o4;
        }
    }
}

// ===========================================================================
// Main attention kernel (v12): GQA HEAD-SHARING of LDS operand reads.
//   r12 floor math: v11's 4.46GB of ds_read_b128 (17.4MB/CU) = ~85us at the
//   measured 85 B/cyc ceiling vs 133us wall -> LDS port is the largest
//   resource. In the swapped formulation K (QK A-op) and V (PV B-op) are
//   HEAD-INDEPENDENT: each wave now processes TWO heads for its 16 q-rows,
//   reading bk/bv once and issuing 2 MFMAs. LDS traffic halves (2.23GB,
//   floor ~43us); MFMA ILP doubles; instruction count per work drops ~35%.
//   Geometry: 256-thread/4-wave blocks (wave = 16-row slot x 2 heads),
//   grid 1024 = 8b x 8hk x 2hp x 8pi; LDS 64KB -> 2 independent blocks/CU,
//   each SIMD runs 2 waves from DIFFERENT blocks. launch_bounds(256,2)
//   -> 256-reg cap (regs ~152, no spill).
//   Keeps v11: in-lane pack via V k-perm, issue-1-ahead single barrier,
//   XOR swizzle, slim softmax, balanced pairing, rsum partials.
// ===========================================================================
__global__ __launch_bounds__(256, 2)
void attn_fwd_v12(const float* __restrict__ qg, const bf16_t* __restrict__ kws,
                  const bf16_t* __restrict__ vtws, float* __restrict__ og)
{
    __shared__ __align__(16) bf16_t Kl[2][KBLK * HDIM];   // 2 x 16KB, [64][128]
    __shared__ __align__(16) bf16_t Vl[2][HDIM * KBLK];   // 2 x 16KB, [128][64]

    const int tid  = threadIdx.x;
    const int w    = tid >> 6;    // 0..3
    const int lane = tid & 63;
    const int l16  = lane & 15;
    const int l4   = lane >> 4;   // 0..3

    const int bid = blockIdx.x;        // 0..1023
    const int hp  = bid & 1;           // head-pair within kv group
    const int bh  = (bid >> 1) & 63;
    const int pi  = bid >> 7;          // 0..7
    const int b   = bh >> 3;
    const int hk  = bh & 7;
    const int fs  = w;                 // 16-row slot in 64-row q-tile
    const int h0  = hk * GQ + hp * 2;  // first of the wave's two heads

    const bf16_t* kbase = kws + (long)(b * SEQ) * KVD + hk * HDIM;
    const bf16_t* vbase = vtws + (long)((b * NKV + hk) * HDIM) * SEQ;

    // ---- tile-invariant per-lane staging offsets (4 K + 4 V chunks/wave) ----
    long koff[4], voff[4];
    int ldst[4];
    #pragma unroll
    for (int i = 0; i < 4; ++i) {
        int c = w * 4 + i;
        int r = c * 4 + (lane >> 4);
        koff[i] = (long)r * KVD + (((lane & 15) ^ (r & 7)) * 8);
        int d = c * 8 + (lane >> 3);
        voff[i] = (long)d * SEQ + (((lane & 7) ^ (d & 7)) * 8);
        ldst[i] = c * 512;
    }
    const long KT_STRIDE = (long)KBLK * KVD;   // 65536 elems

    for (int ph = 0; ph < 2; ++ph) {
        const int qt = ph ? pi : (NQT - 1 - pi);   // heavy q-tile first
        const long qtok0 = (long)b * SEQ + qt * QBLK;

        // ---- Q fragments for BOTH heads (B-op): col=l16, k-slots s*32+l4*8+e ----
        bf16x8 aq[2][4];
        #pragma unroll
        for (int hh = 0; hh < 2; ++hh) {
            const float* qp = qg + (qtok0 + fs * 16 + l16) * QD + (h0 + hh) * HDIM + l4 * 8;
            #pragma unroll
            for (int s = 0; s < 4; ++s) {
                float4 x = *(const float4*)(qp + s * 32);
                float4 y = *(const float4*)(qp + s * 32 + 4);
                bf16x8 t;
                t[0] = (bf16_t)(x.x * QSCL); t[1] = (bf16_t)(x.y * QSCL);
                t[2] = (bf16_t)(x.z * QSCL); t[3] = (bf16_t)(x.w * QSCL);
                t[4] = (bf16_t)(y.x * QSCL); t[5] = (bf16_t)(y.y * QSCL);
                t[6] = (bf16_t)(y.z * QSCL); t[7] = (bf16_t)(y.w * QSCL);
                aq[hh][s] = t;
            }
        }
        __builtin_amdgcn_sched_barrier(0);
        __syncthreads();   // phase boundary: prev phase's LDS reads done

        f32x4 accO[2][8];
        #pragma unroll
        for (int hh = 0; hh < 2; ++hh)
            #pragma unroll
            for (int n = 0; n < 8; ++n) accO[hh][n] = (f32x4){0.f, 0.f, 0.f, 0.f};
        float rsum[2][4];
        #pragma unroll
        for (int hh = 0; hh < 2; ++hh)
            #pragma unroll
            for (int j = 0; j < 4; ++j) rsum[hh][j] = 0.f;

        const bf16_t* kn = kbase;
        const bf16_t* vn = vbase;
        auto issue_tile = [&](int buf) {
            #pragma unroll
            for (int i = 0; i < 4; ++i) gload16(kn + koff[i], &Kl[buf][ldst[i]]);
            #pragma unroll
            for (int i = 0; i < 4; ++i) gload16(vn + voff[i], &Vl[buf][ldst[i]]);
            kn += KT_STRIDE;
            vn += KBLK;
        };

        const int nkt = qt + 1;
        issue_tile(0);

        for (int kt = 0; kt < nkt; ++kt) {
            const bf16_t* Kc = &Kl[kt & 1][0];
            const bf16_t* Vc = &Vl[kt & 1][0];
            // own loads for tile kt are the only outstanding ones here
            asm volatile("s_waitcnt vmcnt(0)" ::: "memory");
            __builtin_amdgcn_s_barrier();
            if (kt + 1 < nkt) issue_tile((kt + 1) & 1);
            __builtin_amdgcn_sched_barrier(0);

            const bool diag = (kt == qt);

            // ---- T = K Q^T per 16-col sub-block; SHARED bk, 2 heads ----
            uint32_t u[2][4][2];
            #pragma unroll
            for (int hh = 0; hh < 2; ++hh)
                #pragma unroll
                for (int kb = 0; kb < 4; ++kb) { u[hh][kb][0] = 0; u[hh][kb][1] = 0; }

            #pragma unroll
            for (int kb = 0; kb < 4; ++kb) {
                const bool skip = diag && (kb > fs);
                if (!skip) {
                    f32x4 t0 = (f32x4){0.f, 0.f, 0.f, 0.f};
                    f32x4 t1 = (f32x4){0.f, 0.f, 0.f, 0.f};
                    __builtin_amdgcn_s_setprio(1);
                    #pragma unroll
                    for (int s = 0; s < 4; ++s) {
                        int elem = (s * 32 + l4 * 8) ^ ((l16 & 7) << 3);
                        bf16x8 bk = *(const bf16x8*)(Kc + (kb * 16 + l16) * 128 + elem);
                        t0 = __builtin_amdgcn_mfma_f32_16x16x32_bf16(bk, aq[0][s], t0, 0, 0, 0);
                        t1 = __builtin_amdgcn_mfma_f32_16x16x32_bf16(bk, aq[1][s], t1, 0, 0, 0);
                    }
                    __builtin_amdgcn_s_setprio(0);
                    const bool needmask = diag && (kb == fs);
                    #pragma unroll
                    for (int j = 0; j < 4; ++j) {
                        const bool m = needmask && (kb * 16 + l4 * 4 + j > fs * 16 + l16);
                        float p0 = exp2f(t0[j]);
                        float p1 = exp2f(t1[j]);
                        if (m) { p0 = 0.f; p1 = 0.f; }
                        t0[j] = p0; t1[j] = p1;
                        rsum[0][j] += p0;
                        rsum[1][j] += p1;
                    }
                    u[0][kb][0] = cvt_pk_bf16(t0[0], t0[1]);
                    u[0][kb][1] = cvt_pk_bf16(t0[2], t0[3]);
                    u[1][kb][0] = cvt_pk_bf16(t1[0], t1[1]);
                    u[1][kb][1] = cvt_pk_bf16(t1[2], t1[3]);
                }
            }

            // ---- P -> PV A-frags: IN-LANE (V k-perm makes B match) ----
            bf16x8 pa[2][2];
            #pragma unroll
            for (int hh = 0; hh < 2; ++hh) {
                #pragma unroll
                for (int ks = 0; ks < 2; ++ks) {
                    union { uint32_t uu[4]; bf16x8 v; } pk;
                    pk.uu[0] = u[hh][ks * 2][0];
                    pk.uu[1] = u[hh][ks * 2][1];
                    pk.uu[2] = u[hh][ks * 2 + 1][0];
                    pk.uu[3] = u[hh][ks * 2 + 1][1];
                    pa[hh][ks] = pk.v;
                }
            }

            // ---- O += P V : SHARED bv, 2 heads ----
            __builtin_amdgcn_s_setprio(1);
            #pragma unroll
            for (int n = 0; n < 8; ++n) {
                #pragma unroll
                for (int ks = 0; ks < 2; ++ks) {
                    int elem = (ks * 32 + l4 * 8) ^ ((l16 & 7) << 3);
                    bf16x8 bv = *(const bf16x8*)(Vc + (n * 16 + l16) * 64 + elem);
                    accO[0][n] = __builtin_amdgcn_mfma_f32_16x16x32_bf16(pa[0][ks], bv, accO[0][n], 0, 0, 0);
                    accO[1][n] = __builtin_amdgcn_mfma_f32_16x16x32_bf16(pa[1][ks], bv, accO[1][n], 0, 0, 0);
                }
            }
            __builtin_amdgcn_s_setprio(0);
            // no end-of-tile barrier (issue-1-ahead scheme)
        }

        // ---- epilogue: per head combine partials, reduce over l4, store ----
        #pragma unroll
        for (int hh = 0; hh < 2; ++hh) {
            float rs = (rsum[hh][0] + rsum[hh][1]) + (rsum[hh][2] + rsum[hh][3]);
            rs += __shfl_xor(rs, 16);
            rs += __shfl_xor(rs, 32);
            float inv = 1.f / rs;   // valid for q-row = l16 on every lane
            #pragma unroll
            for (int j = 0; j < 4; ++j) {
                const int qr = l4 * 4 + j;
                float invr = __shfl(inv, qr);   // lane qr holds q-row qr's inv
                float* op = og + (qtok0 + fs * 16 + qr) * QD + (h0 + hh) * HDIM + l16;
                #pragma unroll
                for (int n = 0; n < 8; ++n)
                    op[n * 16] = accO[hh][n][j] * invr;
            }
        }
    }
}

// ===========================================================================
// Fallback (round-1 kernel) if ws is too small for the bf16 pre-pass.
// ===========================================================================
#define KPAD 136
#define VPAD 72
#define PPAD 72
__global__ __launch_bounds__(512, 2)
void attn_fwd_v1(const float* __restrict__ qg, const float* __restrict__ kg,
                 const float* __restrict__ vg, float* __restrict__ og)
{
    __shared__ bf16_t Kl[KBLK * KPAD];
    __shared__ bf16_t Vt[HDIM * VPAD];
    __shared__ bf16_t Pl[8 * 16 * PPAD];

    const int tid  = threadIdx.x;
    const int w    = tid >> 6;
    const int lane = tid & 63;
    const int l4   = lane >> 4;
    const int l16  = lane & 15;

    const int bid = blockIdx.x;
    const int bh  = bid % 64;
    const int qt  = (NQT - 1) - bid / 64;
    const int b   = bh / NKV;
    const int hk  = bh % NKV;
    const int g   = w >> 1;
    const int h   = hk * GQ + g;
    const int rh  = (w & 1) * 32;

    const long qtok0 = (long)b * SEQ + qt * QBLK;

    bf16x8 aq[2][4];
    #pragma unroll
    for (int f = 0; f < 2; ++f) {
        const float* qp = qg + (qtok0 + rh + f * 16 + l16) * QD + h * HDIM + l4 * 8;
        #pragma unroll
        for (int s = 0; s < 4; ++s) {
            float4 x = *(const float4*)(qp + s * 32);
            float4 y = *(const float4*)(qp + s * 32 + 4);
            bf16x8 t;
            t[0] = (bf16_t)x.x; t[1] = (bf16_t)x.y; t[2] = (bf16_t)x.z; t[3] = (bf16_t)x.w;
            t[4] = (bf16_t)y.x; t[5] = (bf16_t)y.y; t[6] = (bf16_t)y.z; t[7] = (bf16_t)y.w;
            aq[f][s] = t;
        }
    }

    f32x4 accO[2][8];
    float mrun[2][4], lsum[2][4];
    #pragma unroll
    for (int f = 0; f < 2; ++f) {
        #pragma unroll
        for (int n = 0; n < 8; ++n) accO[f][n] = (f32x4){0.f, 0.f, 0.f, 0.f};
        #pragma unroll
        for (int j = 0; j < 4; ++j) { mrun[f][j] = -1e30f; lsum[f][j] = 0.f; }
    }

    const long ktok0 = (long)b * SEQ;
    const int nkt = qt + 1;

    for (int kt = 0; kt < nkt; ++kt) {
        __syncthreads();
        const float* kp = kg + (ktok0 + kt * KBLK) * KVD + hk * HDIM;
        const float* vp = vg + (ktok0 + kt * KBLK) * KVD + hk * HDIM;
        #pragma unroll
        for (int it = 0; it < 4; ++it) {
            int idx = it * 512 + tid;
            int row = idx >> 5;
            int c4  = (idx & 31) * 4;
            float4 kf = *(const float4*)(kp + (long)row * KVD + c4);
            bf16x4 k4;
            k4[0] = (bf16_t)kf.x; k4[1] = (bf16_t)kf.y; k4[2] = (bf16_t)kf.z; k4[3] = (bf16_t)kf.w;
            *(bf16x4*)(&Kl[row * KPAD + c4]) = k4;
            float4 vf = *(const float4*)(vp + (long)row * KVD + c4);
            const float* vfa = (const float*)&vf;
            #pragma unroll
            for (int m = 0; m < 4; ++m) {
                int d   = c4 + m;
                int blk = (row >> 3) ^ ((d >> 3) & 7);
                Vt[d * VPAD + blk * 8 + (row & 7)] = (bf16_t)vfa[m];
            }
        }
        __syncthreads();

        const bool diag = (kt == qt);
        bf16_t* pw = &Pl[w * 16 * PPAD];

        #pragma unroll
        for (int f = 0; f < 2; ++f) {
            f32x4 accS[4];
            #pragma unroll
            for (int n = 0; n < 4; ++n) {
                f32x4 acc = (f32x4){0.f, 0.f, 0.f, 0.f};
                #pragma unroll
                for (int s = 0; s < 4; ++s) {
                    bf16x8 bk = *(const bf16x8*)(&Kl[(n * 16 + l16) * KPAD + s * 32 + l4 * 8]);
                    acc = __builtin_amdgcn_mfma_f32_16x16x32_bf16(aq[f][s], bk, acc, 0, 0, 0);
                }
                accS[n] = acc;
            }

            const int qrow_loc = rh + f * 16 + l4 * 4;
            float pm[4];
            #pragma unroll
            for (int j = 0; j < 4; ++j) pm[j] = -1e30f;
            #pragma unroll
            for (int n = 0; n < 4; ++n) {
                #pragma unroll
                for (int j = 0; j < 4; ++j) {
                    float sv = accS[n][j] * ATT_SCALE;
                    if (diag && (n * 16 + l16 > qrow_loc + j)) sv = -1e30f;
                    accS[n][j] = sv;
                    pm[j] = fmaxf(pm[j], sv);
                }
            }
            #pragma unroll
            for (int j = 0; j < 4; ++j) {
                float m0 = pm[j];
                m0 = fmaxf(m0, __shfl_xor(m0, 1));
                m0 = fmaxf(m0, __shfl_xor(m0, 2));
                m0 = fmaxf(m0, __shfl_xor(m0, 4));
                m0 = fmaxf(m0, __shfl_xor(m0, 8));
                pm[j] = m0;
            }
            float al[4], rs[4];
            #pragma unroll
            for (int j = 0; j < 4; ++j) {
                float mnew = fmaxf(mrun[f][j], pm[j]);
                al[j] = __expf(mrun[f][j] - mnew);
                mrun[f][j] = mnew;
                rs[j] = 0.f;
            }
            #pragma unroll
            for (int n = 0; n < 4; ++n) {
                #pragma unroll
                for (int j = 0; j < 4; ++j) {
                    float p = __expf(accS[n][j] - mrun[f][j]);
                    accS[n][j] = p;
                    rs[j] += p;
                }
            }
            #pragma unroll
            for (int j = 0; j < 4; ++j) {
                float r = rs[j];
                r += __shfl_xor(r, 1);
                r += __shfl_xor(r, 2);
                r += __shfl_xor(r, 4);
                r += __shfl_xor(r, 8);
                lsum[f][j] = lsum[f][j] * al[j] + r;
            }
            #pragma unroll
            for (int n = 0; n < 8; ++n) {
                #pragma unroll
                for (int j = 0; j < 4; ++j) accO[f][n][j] *= al[j];
            }
            #pragma unroll
            for (int n = 0; n < 4; ++n) {
                #pragma unroll
                for (int j = 0; j < 4; ++j)
                    pw[(l4 * 4 + j) * PPAD + n * 16 + l16] = (bf16_t)accS[n][j];
            }
            asm volatile("s_waitcnt lgkmcnt(0)" ::: "memory");
            __builtin_amdgcn_sched_barrier(0);
            #pragma unroll
            for (int ks = 0; ks < 2; ++ks) {
                bf16x8 ap = *(const bf16x8*)(&pw[l16 * PPAD + ks * 32 + l4 * 8]);
                #pragma unroll
                for (int n = 0; n < 8; ++n) {
                    int d   = n * 16 + l16;
                    int blk = (ks * 4 + l4) ^ ((d >> 3) & 7);
                    bf16x8 bv = *(const bf16x8*)(&Vt[d * VPAD + blk * 8]);
                    accO[f][n] = __builtin_amdgcn_mfma_f32_16x16x32_bf16(ap, bv, accO[f][n], 0, 0, 0);
                }
            }
        }
    }

    #pragma unroll
    for (int f = 0; f < 2; ++f) {
        #pragma unroll
        for (int j = 0; j < 4; ++j) {
            float inv = 1.f / lsum[f][j];
            float* op = og + (qtok0 + rh + f * 16 + l4 * 4 + j) * QD + h * HDIM;
            #pragma unroll
            for (int n = 0; n < 8; ++n)
                op[n * 16 + l16] = accO[f][n][j] * inv;
        }
    }
}

extern "C" void kernel_launch(void* const* d_in, const int* in_sizes, int n_in,
                              void* d_out, int out_size, void* d_ws, size_t ws_size,
                              hipStream_t stream) {
    const float* q = (const float*)d_in[0];
    const float* k = (const float*)d_in[1];
    const float* v = (const float*)d_in[2];
    float* o = (float*)d_out;

    const size_t kws_elems = (size_t)TOTAL * KVD;            // 8,388,608
    const size_t vws_elems = (size_t)BATCH * NKV * HDIM * SEQ;
    const size_t need = (kws_elems + vws_elems) * sizeof(bf16_t);  // 33.5 MB

    if (ws_size >= need) {
        bf16_t* kws  = (bf16_t*)d_ws;
        bf16_t* vtws = kws + kws_elems;
        attn_prepass_kernel<<<1536, 256, 0, stream>>>(k, v, kws, vtws);
        attn_fwd_v12<<<1024, 256, 0, stream>>>(q, kws, vtws, o);
    } else {
        attn_fwd_v1<<<NQT * BATCH * NKV, 512, 0, stream>>>(q, k, v, o);
    }
}